// Round 2
// 679.646 us; speedup vs baseline: 1.0074x; 1.0074x over previous
//
#include <hip/hip_runtime.h>

// SlotAttention, algebraically restructured:
//   logits = (LN(slots) @ (Wq^T @ Wk)) . x / 16   (q.bk term dropped: softmax-invariant)
//   updates = softmax-weighted-avg(x) @ Wv^T + bv  (attn rows sum to 1)
// -> k, v never materialized. x converted to bf16 once (L3-resident for iters 2,3).
// R2: attention on MFMA (16x16x32 bf16).
// R4: k_upd with gates fused in C-layout registers; static LDS 58.4 KB.
// R5: k_attn producer-consumer wave split: waves 0-1 do phase A(c) while waves
//     2-3 do phase B(c-1); 2 barriers/chunk (was 3); v_perm_b32 repack replaces
//     divergent hi/lo branch; k_init fused into k_qk0; k_wqk emits bf16 WqkT.
// R6: identical resubmit (R5 bench died to container-acquire infra failure).

constexpr int Bn = 64;    // batch
constexpr int Nn = 4096;  // inputs per batch
constexpr int Dd = 256;   // feature dim (== IN_D)
constexpr int Ss = 8;     // slots
constexpr int CH = 16;    // N-chunks per batch for attention
constexpr float EPSF = 1e-5f;

#define DEV __device__ __forceinline__

using short8 = __attribute__((ext_vector_type(8))) short;
using f32x4 = __attribute__((ext_vector_type(4))) float;
union U8 { short8 s; uint4 u; };

DEV unsigned bfpack2(float lo, float hi) {
  unsigned ul = __float_as_uint(lo), uh = __float_as_uint(hi);
  ul = (ul + 0x7FFFu + ((ul >> 16) & 1u)) >> 16;         // RNE to bf16
  uh = (uh + 0x7FFFu + ((uh >> 16) & 1u)) & 0xFFFF0000u;
  return ul | uh;
}
DEV unsigned short bf16r(float x) {
  unsigned u = __float_as_uint(x);
  u = (u + 0x7FFFu + ((u >> 16) & 1u)) >> 16;
  return (unsigned short)u;
}
DEV float rsum32(float v) {  // sum within each 32-lane half of a wave
  v += __shfl_xor(v, 1); v += __shfl_xor(v, 2); v += __shfl_xor(v, 4);
  v += __shfl_xor(v, 8); v += __shfl_xor(v, 16);
  return v;
}
DEV float sigm(float x) { return 1.f / (1.f + __expf(-x)); }

// ---- MFMA tile helpers: C[row=quad*4+r][col=t*16+m16] = sum_k A[row][k] W[col][k] + b
template <int NK>
DEV void load_af(short8* a, const unsigned short* base, int lda, int m16, int quad) {
  const unsigned short* p = base + m16 * lda + quad * 8;
#pragma unroll
  for (int kk = 0; kk < NK; ++kk) a[kk] = *(const short8*)(p + kk * 32);
}
template <int NK>
DEV f32x4 gemm_tile(const short8* a, const unsigned short* wr, float binit) {
  f32x4 acc = {binit, binit, binit, binit};
#pragma unroll
  for (int kk = 0; kk < NK; ++kk) {
    short8 b = *(const short8*)(wr + kk * 32);
    acc = __builtin_amdgcn_mfma_f32_16x16x32_bf16(a[kk], b, acc, 0, 0, 0);
  }
  return acc;
}

// LayerNorm over one 256-row held 8-per-thread by 32 lanes; writes bf16 packed out.
DEV void ln_row8(const float* x, const float* g, const float* b, int d0,
                 unsigned short* dst) {
  float s = x[0] + x[1] + x[2] + x[3] + x[4] + x[5] + x[6] + x[7];
  float mu = rsum32(s) * (1.f / 256.f);
  float q = 0.f;
#pragma unroll
  for (int j = 0; j < 8; ++j) { float d = x[j] - mu; q += d * d; }
  float rs = rsqrtf(rsum32(q) * (1.f / 256.f) + EPSF);
  float o[8];
#pragma unroll
  for (int j = 0; j < 8; ++j) o[j] = (x[j] - mu) * rs * g[d0 + j] + b[d0 + j];
  uint4 w;
  w.x = bfpack2(o[0], o[1]); w.y = bfpack2(o[2], o[3]);
  w.z = bfpack2(o[4], o[5]); w.w = bfpack2(o[6], o[7]);
  *(uint4*)dst = w;
}

// ---------------- Wqk_b[c][d] = bf16(sum_e Wq[e][d]*Wk[e][c]); bqk[c] = sum_e bq[e]*Wk[e][c]
__global__ __launch_bounds__(256) void k_wqk(const float* __restrict__ Wq,
                                             const float* __restrict__ Wk,
                                             const float* __restrict__ bq,
                                             unsigned short* __restrict__ Wqk_b,
                                             float* __restrict__ bqk) {
  int tid = threadIdx.x, c = blockIdx.x;
  if (c < 256) {
    float acc = 0.f;
    for (int e = 0; e < 256; ++e) acc += Wq[e * 256 + tid] * Wk[e * 256 + c];
    Wqk_b[c * 256 + tid] = bf16r(acc);
  } else {
    float acc = 0.f;
    for (int e = 0; e < 256; ++e) acc += bq[e] * Wk[e * 256 + tid];
    bqk[tid] = acc;
  }
}

// ---------------- convert weights to bf16 (+ zr-cat + bzr) ----------------
__global__ __launch_bounds__(256) void k_conv(
    const float* __restrict__ Wv, const float* __restrict__ Wih,
    const float* __restrict__ Whh, const float* __restrict__ W1,
    const float* __restrict__ W2,
    const float* __restrict__ bih, const float* __restrict__ bhh,
    unsigned* Wv_b, unsigned* Wzr_b, unsigned* Win_b, unsigned* Whn_b,
    unsigned* W1_b, unsigned* W2_b, float* bzr) {
  if (blockIdx.x >= 1152) {
    int i = (blockIdx.x - 1152) * 256 + threadIdx.x;
    if (i < 512) bzr[i] = bih[i] + bhh[i];
    return;
  }
  int p = blockIdx.x * 256 + threadIdx.x;  // bf16-pair index
  const float* src; unsigned* dst;
  if (p < 32768) { src = Wv + 2 * p; dst = Wv_b + p; }
  else if (p < 163840) {
    int q = p - 32768, row = q >> 8, col = (q & 255) * 2;
    src = (col < 256) ? (Wih + row * 256 + col) : (Whh + row * 256 + col - 256);
    dst = Wzr_b + q;
  }
  else if (p < 196608) { int q = p - 163840; src = Wih + 512 * 256 + 2 * q; dst = Win_b + q; }
  else if (p < 229376) { int q = p - 196608; src = Whh + 512 * 256 + 2 * q; dst = Whn_b + q; }
  else if (p < 262144) { int q = p - 229376; src = W1 + 2 * q; dst = W1_b + q; }
  else { int q = p - 262144; src = W2 + 2 * q; dst = W2_b + q; }
  dst[0] = bfpack2(src[0], src[1]);
}

// ---------------- slots = mu + sigma*noise; q' = (LN(slots)@WqkT + bqk)/16 ----------------
__global__ __launch_bounds__(512) void k_qk0(const float* __restrict__ noise,
                                             const float* __restrict__ s_mu,
                                             const float* __restrict__ s_sg,
                                             const float* __restrict__ gsl,
                                             const float* __restrict__ bsl,
                                             const unsigned short* __restrict__ Wqk_b,
                                             const float* __restrict__ bqk,
                                             float* __restrict__ slots,
                                             float* __restrict__ qk) {
  __shared__ __align__(16) unsigned short lnb[16 * 264];
  const int tid = threadIdx.x, bb = blockIdx.x;
  const int lane = tid & 63, wave = tid >> 6;
  const int m16 = lane & 15, quad = lane >> 4;
  const int row = tid >> 5, l32 = tid & 31, d0 = l32 * 8;
  {
    const int grow = bb * 16 + row;            // = b*8 + s
    const int sidx = (grow & 7) * 256 + d0;
    const float* np = noise + (size_t)grow * 256 + d0;
    float4 n0 = *(const float4*)np, n1 = *(const float4*)(np + 4);
    float4 m0 = *(const float4*)(s_mu + sidx), m1 = *(const float4*)(s_mu + sidx + 4);
    float4 g0 = *(const float4*)(s_sg + sidx), g1 = *(const float4*)(s_sg + sidx + 4);
    float x[8] = {m0.x + g0.x * n0.x, m0.y + g0.y * n0.y,
                  m0.z + g0.z * n0.z, m0.w + g0.w * n0.w,
                  m1.x + g1.x * n1.x, m1.y + g1.y * n1.y,
                  m1.z + g1.z * n1.z, m1.w + g1.w * n1.w};
    float* sp_ = slots + (size_t)grow * 256 + d0;
    float4 o0, o1;
    o0.x = x[0]; o0.y = x[1]; o0.z = x[2]; o0.w = x[3];
    o1.x = x[4]; o1.y = x[5]; o1.z = x[6]; o1.w = x[7];
    *(float4*)sp_ = o0; *(float4*)(sp_ + 4) = o1;
    ln_row8(x, gsl, bsl, d0, lnb + row * 264 + d0);
  }
  __syncthreads();
  short8 a8[8];
  load_af<8>(a8, lnb, 264, m16, quad);
#pragma unroll
  for (int i = 0; i < 2; ++i) {
    int t = wave + 8 * i;
    f32x4 acc = gemm_tile<8>(a8, Wqk_b + (size_t)(t * 16 + m16) * 256 + quad * 8,
                             bqk[t * 16 + m16]);
#pragma unroll
    for (int r = 0; r < 4; ++r)
      qk[(size_t)(bb * 16 + quad * 4 + r) * 256 + t * 16 + m16] = acc[r] * 0.0625f;
  }
}

// ---------------- MFMA attention pass ----------------
template <bool FIRST>
DEV void ld_chunk(const float* __restrict__ xin, unsigned* __restrict__ xbf,
                  size_t nbase, int tid, uint4* pr) {
#pragma unroll
  for (int i = 0; i < 4; ++i) {
    int flat = i * 256 + tid, n = flat >> 5, od = flat & 31;
    if (FIRST) {
      const float4* src = (const float4*)(xin + (nbase + n) * 256 + od * 8);
      float4 v0 = src[0], v1 = src[1];
      uint4 o;
      o.x = bfpack2(v0.x, v0.y); o.y = bfpack2(v0.z, v0.w);
      o.z = bfpack2(v1.x, v1.y); o.w = bfpack2(v1.z, v1.w);
      ((uint4*)xbf)[(nbase + n) * 32 + od] = o;
      pr[i] = o;
    } else {
      pr[i] = ((const uint4*)xbf)[(nbase + n) * 32 + od];
    }
  }
}

// Wave-specialized pipeline: per barrier-interval, waves 0-1 run phase A (P^T =
// q @ X^T, exp, l-partials) on chunk ch while waves 2-3 run phase B
// (U^T += X^T @ P, 8 d-tiles each) on chunk ch-1. xt and pp double-buffered.
template <bool FIRST>
__global__ __launch_bounds__(256) void k_attn(const float* __restrict__ xin,
                                              unsigned* __restrict__ xbf,
                                              const float* __restrict__ qk,
                                              float* __restrict__ pl,
                                              float* __restrict__ pu) {
  __shared__ __align__(16) unsigned xt[2][128 * 33];
  __shared__ __align__(16) unsigned pp[2][16 * 17];
  __shared__ __align__(16) float lred[2][16];
  const int tid = threadIdx.x;
  const int lane = tid & 63, wave = tid >> 6;
  const int m16 = lane & 15, quad = lane >> 4;
  const int c = blockIdx.x, b = blockIdx.y;
  const int pb = (b * CH + c) * 8;
  const bool isA = (wave < 2);
  // v_perm selector: even d -> lo16 of each dword pair, odd d -> hi16
  const unsigned psel = (m16 & 1) ? 0x07060302u : 0x05040100u;

  // q A-frags: lane holds q[s=m16][k=quad*8+j]; s>=8 -> zero (A-waves only)
  short8 aq[8];
  if (isA) {
    const float* qrow = qk + (size_t)(b * 8 + (m16 & 7)) * 256 + quad * 8;
#pragma unroll
    for (int kk = 0; kk < 8; ++kk) {
      U8 f;
      float4 q0 = *(const float4*)(qrow + kk * 32);
      float4 q1 = *(const float4*)(qrow + kk * 32 + 4);
      f.u.x = bfpack2(q0.x, q0.y); f.u.y = bfpack2(q0.z, q0.w);
      f.u.z = bfpack2(q1.x, q1.y); f.u.w = bfpack2(q1.z, q1.w);
      if (m16 >= 8) { f.u.x = 0u; f.u.y = 0u; f.u.z = 0u; f.u.w = 0u; }
      aq[kk] = f.s;
    }
  }
  float lacc[4] = {0.f, 0.f, 0.f, 0.f};
  f32x4 acc[8];
#pragma unroll
  for (int t = 0; t < 8; ++t) acc[t] = (f32x4){0.f, 0.f, 0.f, 0.f};

  uint4 pr[4];
  const size_t nb0 = (size_t)b * Nn + (size_t)c * 256;
  ld_chunk<FIRST>(xin, xbf, nb0, tid, pr);

  for (int ch = 0; ch <= 8; ++ch) {
    if (ch < 8) {
      unsigned* xtb = xt[ch & 1];
      // ---- stage from regs: X^T pair-packed [pair-d][33] ----
#pragma unroll
      for (int i = 0; i < 4; ++i) {
        int flat = i * 256 + tid, n = flat >> 5, od = flat & 31, rb = od * 4;
        xtb[(rb + 0) * 33 + n] = pr[i].x;
        xtb[(rb + 1) * 33 + n] = pr[i].y;
        xtb[(rb + 2) * 33 + n] = pr[i].z;
        xtb[(rb + 3) * 33 + n] = pr[i].w;
      }
    }
    __syncthreads();
    if (ch + 1 < 8)  // prefetch next chunk (overlaps A/B phase)
      ld_chunk<FIRST>(xin, xbf, nb0 + (size_t)(ch + 1) * 32, tid, pr);
    if (isA) {
      if (ch < 8) {
        // ---- phase A(ch): P^T = q @ X^T, exp, l-partials ----
        const unsigned* xtb = xt[ch & 1];
        f32x4 pacc = (f32x4){0.f, 0.f, 0.f, 0.f};
#pragma unroll
        for (int kk = 0; kk < 8; ++kk) {
          int base = (kk * 16 + quad * 4) * 33 + wave * 16 + m16;
          U8 bf;
          bf.u.x = xtb[base]; bf.u.y = xtb[base + 33];
          bf.u.z = xtb[base + 66]; bf.u.w = xtb[base + 99];
          pacc = __builtin_amdgcn_mfma_f32_16x16x32_bf16(aq[kk], bf.s, pacc, 0, 0, 0);
        }
        const int xrow = wave * 16 + m16;
        unsigned short* pps = (unsigned short*)pp[ch & 1];
#pragma unroll
        for (int r = 0; r < 4; ++r) {
          float p = __expf(pacc[r]);  // |logit| small: no max-shift needed
          lacc[r] += p;
          pps[((xrow >> 1) * 17 + quad * 4 + r) * 2 + (xrow & 1)] = bf16r(p);
        }
      }
    } else if (ch >= 1) {
      // ---- phase B(ch-1): U^T += X^T @ P (this wave owns 128 d-cols) ----
      const unsigned* xtb = xt[(ch - 1) & 1];
      const unsigned* ppb = pp[(ch - 1) & 1];
      U8 bp;
      bp.u.x = ppb[(quad * 4 + 0) * 17 + m16];
      bp.u.y = ppb[(quad * 4 + 1) * 17 + m16];
      bp.u.z = ppb[(quad * 4 + 2) * 17 + m16];
      bp.u.w = ppb[(quad * 4 + 3) * 17 + m16];
#pragma unroll
      for (int t = 0; t < 8; ++t) {
        int d = (wave - 2) * 128 + t * 16 + m16;
        const unsigned* xr = xtb + (d >> 1) * 33 + quad * 8;
        unsigned u0 = xr[0], u1 = xr[1], u2 = xr[2], u3 = xr[3];
        unsigned u4 = xr[4], u5 = xr[5], u6 = xr[6], u7 = xr[7];
        U8 af;
        af.u.x = __builtin_amdgcn_perm(u1, u0, psel);
        af.u.y = __builtin_amdgcn_perm(u3, u2, psel);
        af.u.z = __builtin_amdgcn_perm(u5, u4, psel);
        af.u.w = __builtin_amdgcn_perm(u7, u6, psel);
        acc[t] = __builtin_amdgcn_mfma_f32_16x16x32_bf16(af.s, bp.s, acc[t], 0, 0, 0);
      }
    }
    __syncthreads();
  }
  if (!isA && m16 < 8) {
    const int d0w = (wave - 2) * 128;
#pragma unroll
    for (int t = 0; t < 8; ++t)
#pragma unroll
      for (int r = 0; r < 4; ++r)
        pu[(size_t)(pb + m16) * 256 + d0w + t * 16 + quad * 4 + r] = acc[t][r];
  }
  if (isA) {
#pragma unroll
    for (int r = 0; r < 4; ++r) {
      float v = lacc[r];
      v += __shfl_xor(v, 1); v += __shfl_xor(v, 2);
      v += __shfl_xor(v, 4); v += __shfl_xor(v, 8);
      if (m16 == 0) lred[wave][quad * 4 + r] = v;
    }
  }
  __syncthreads();
  if (tid < 8) pl[pb + tid] = lred[0][tid] + lred[1][tid];
}

// ---------------- fused slot update: combine+Wv+GRU+MLP+LN+next-q' ----------------
// 32 blocks x 512 threads; block = 16 rows (2 batches x 8 slots).
// GRU gates fused in C-layout registers: wave w owns output cols of tiles {w, w+8}
// for r, z, i_n, h_n alike -> no LDS round-trip for gates. Static LDS = 58.4 KB.
__global__ __launch_bounds__(512) void k_upd(
    const float* __restrict__ pl, const float* __restrict__ pu,
    const unsigned short* __restrict__ Wv_b, const float* __restrict__ bv,
    const unsigned short* __restrict__ Wzr_b, const float* __restrict__ bzr,
    const unsigned short* __restrict__ Win_b, const float* __restrict__ bin,
    const unsigned short* __restrict__ Whn_b, const float* __restrict__ bhn,
    const unsigned short* __restrict__ W1_b, const float* __restrict__ b1,
    const unsigned short* __restrict__ W2_b, const float* __restrict__ b2,
    const float* __restrict__ gml, const float* __restrict__ bml,
    const float* __restrict__ gsl, const float* __restrict__ bsl,
    const unsigned short* __restrict__ Wqk_b, const float* __restrict__ bqk,
    float* __restrict__ slots, float* __restrict__ qk, float* __restrict__ dout) {
  __shared__ __align__(16) unsigned short cat[16 * 520];  // [u'|h] -> [upd|h]; hid in [0:256)
  __shared__ __align__(16) float sp[16 * 260];            // h_prev; later slots2
  __shared__ __align__(16) float s1[16 * 260];            // slots1 (post-GRU residual)
  __shared__ __align__(16) unsigned short lnb[16 * 264];  // LN output bf16 (A operand)
  const int tid = threadIdx.x, bb = blockIdx.x;
  const int lane = tid & 63, wave = tid >> 6;
  const int m16 = lane & 15, quad = lane >> 4;
  const int row = tid >> 5, l32 = tid & 31, d0 = l32 * 8;
  const int bat = 2 * bb + (row >> 3), sl = row & 7;
  // ---- 1: combine chunk partials -> u' bf16; h_prev -> sp f32 + cat bf16 ----
  {
    float L = 0.f;
#pragma unroll
    for (int cc = 0; cc < 16; ++cc) L += pl[(bat * 16 + cc) * 8 + sl];
    float li = 1.f / L;
    float a[8] = {0.f, 0.f, 0.f, 0.f, 0.f, 0.f, 0.f, 0.f};
    for (int cc = 0; cc < 16; ++cc) {
      const float* pp_ = pu + ((size_t)(bat * 16 + cc) * 8 + sl) * 256 + d0;
      float4 v0 = *(const float4*)pp_, v1 = *(const float4*)(pp_ + 4);
      a[0] += v0.x; a[1] += v0.y; a[2] += v0.z; a[3] += v0.w;
      a[4] += v1.x; a[5] += v1.y; a[6] += v1.z; a[7] += v1.w;
    }
    uint4 o;
    o.x = bfpack2(a[0] * li, a[1] * li); o.y = bfpack2(a[2] * li, a[3] * li);
    o.z = bfpack2(a[4] * li, a[5] * li); o.w = bfpack2(a[6] * li, a[7] * li);
    *(uint4*)(cat + row * 520 + d0) = o;
    const float* sp_ = slots + (size_t)(bb * 16 + row) * 256 + d0;
    float4 h0 = *(const float4*)sp_, h1 = *(const float4*)(sp_ + 4);
    *(float4*)(sp + row * 260 + d0) = h0;
    *(float4*)(sp + row * 260 + d0 + 4) = h1;
    uint4 hb;
    hb.x = bfpack2(h0.x, h0.y); hb.y = bfpack2(h0.z, h0.w);
    hb.z = bfpack2(h1.x, h1.y); hb.w = bfpack2(h1.z, h1.w);
    *(uint4*)(cat + row * 520 + 256 + d0) = hb;
  }
  __syncthreads();
  // ---- 2: updates = u' @ Wv^T + bv (regs), then -> cat[:,0:256) bf16 ----
  short8 afr[16];
  load_af<8>(afr, cat, 520, m16, quad);
  f32x4 accv[2];
#pragma unroll
  for (int i = 0; i < 2; ++i) {
    int t = wave + 8 * i;
    accv[i] = gemm_tile<8>(afr, Wv_b + (size_t)(t * 16 + m16) * 256 + quad * 8,
                           bv[t * 16 + m16]);
  }
  __syncthreads();
#pragma unroll
  for (int i = 0; i < 2; ++i) {
    int t = wave + 8 * i;
#pragma unroll
    for (int r = 0; r < 4; ++r)
      cat[(quad * 4 + r) * 520 + t * 16 + m16] = bf16r(accv[i][r]);
  }
  __syncthreads();
  // ---- 3: r,z = sigmoid([upd|h] @ Wzr^T + bzr), kept in C-layout regs ----
  load_af<16>(afr, cat, 520, m16, quad);
  f32x4 rr[2], zz[2];
#pragma unroll
  for (int i = 0; i < 2; ++i) {
    int t = wave + 8 * i;
    f32x4 ar = gemm_tile<16>(afr, Wzr_b + (size_t)(t * 16 + m16) * 512 + quad * 8,
                             bzr[t * 16 + m16]);
    f32x4 az = gemm_tile<16>(afr, Wzr_b + (size_t)((t + 16) * 16 + m16) * 512 + quad * 8,
                             bzr[(t + 16) * 16 + m16]);
#pragma unroll
    for (int r = 0; r < 4; ++r) { rr[i][r] = sigm(ar[r]); zz[i][r] = sigm(az[r]); }
  }
  // ---- 4: i_n, h_n (same cols as r,z) -> gate fused in regs -> s1 ----
#pragma unroll
  for (int i = 0; i < 2; ++i) {
    int t = wave + 8 * i, col = t * 16 + m16;
    f32x4 ain = gemm_tile<8>(afr, Win_b + (size_t)(t * 16 + m16) * 256 + quad * 8,
                             bin[col]);
    f32x4 ahn = gemm_tile<8>(afr + 8, Whn_b + (size_t)(t * 16 + m16) * 256 + quad * 8,
                             bhn[col]);
#pragma unroll
    for (int r = 0; r < 4; ++r) {
      int rw = quad * 4 + r;
      float nin = ain[r] + rr[i][r] * ahn[r];
      float nn = 1.f - 2.f / (__expf(2.f * nin) + 1.f);  // tanh
      float hpc = sp[rw * 260 + col];
      s1[rw * 260 + col] = hpc + (1.f - zz[i][r]) * nn + zz[i][r] * hpc;  // prev + h_new
    }
  }
  __syncthreads();
  // ---- 5: LN_mlp(slots1) -> lnb ----
  {
    const float* s1r = s1 + row * 260 + d0;
    float4 v0 = *(const float4*)s1r, v1 = *(const float4*)(s1r + 4);
    float x[8] = {v0.x, v0.y, v0.z, v0.w, v1.x, v1.y, v1.z, v1.w};
    ln_row8(x, gml, bml, d0, lnb + row * 264 + d0);
  }
  __syncthreads();
  // ---- 6: hid = relu(LN_mlp @ W1^T + b1) -> cat[:,0:256) ----
  load_af<8>(afr, lnb, 264, m16, quad);
#pragma unroll
  for (int i = 0; i < 2; ++i) {
    int t = wave + 8 * i;
    f32x4 acc = gemm_tile<8>(afr, W1_b + (size_t)(t * 16 + m16) * 256 + quad * 8,
                             b1[t * 16 + m16]);
#pragma unroll
    for (int r = 0; r < 4; ++r)
      cat[(quad * 4 + r) * 520 + t * 16 + m16] = bf16r(fmaxf(acc[r], 0.f));
  }
  __syncthreads();
  // ---- 7: slots2 = slots1 + hid @ W2^T + b2 -> global + sp(reuse) ----
  load_af<8>(afr, cat, 520, m16, quad);
#pragma unroll
  for (int i = 0; i < 2; ++i) {
    int t = wave + 8 * i;
    f32x4 acc = gemm_tile<8>(afr, W2_b + (size_t)(t * 16 + m16) * 256 + quad * 8,
                             b2[t * 16 + m16]);
#pragma unroll
    for (int r = 0; r < 4; ++r) {
      int rw = quad * 4 + r, col = t * 16 + m16;
      float v = acc[r] + s1[rw * 260 + col];
      size_t gi = (size_t)(bb * 16 + rw) * 256 + col;
      slots[gi] = v;
      if (dout) dout[gi] = v;
      sp[rw * 260 + col] = v;
    }
  }
  __syncthreads();
  // ---- 8: LN_slots(slots2) -> lnb ----
  {
    const float* spr = sp + row * 260 + d0;
    float4 v0 = *(const float4*)spr, v1 = *(const float4*)(spr + 4);
    float x[8] = {v0.x, v0.y, v0.z, v0.w, v1.x, v1.y, v1.z, v1.w};
    ln_row8(x, gsl, bsl, d0, lnb + row * 264 + d0);
  }
  __syncthreads();
  // ---- 9: q' = (LN_slots @ WqkT + bqk)/16 ----
  load_af<8>(afr, lnb, 264, m16, quad);
#pragma unroll
  for (int i = 0; i < 2; ++i) {
    int t = wave + 8 * i;
    f32x4 acc = gemm_tile<8>(afr, Wqk_b + (size_t)(t * 16 + m16) * 256 + quad * 8,
                             bqk[t * 16 + m16]);
#pragma unroll
    for (int r = 0; r < 4; ++r)
      qk[(size_t)(bb * 16 + quad * 4 + r) * 256 + t * 16 + m16] = acc[r] * 0.0625f;
  }
}

// ---------------- launch ----------------
extern "C" void kernel_launch(void* const* d_in, const int* in_sizes, int n_in,
                              void* d_out, int out_size, void* d_ws, size_t ws_size,
                              hipStream_t stream) {
  const float* inputs = (const float*)d_in[0];
  const float* noise = (const float*)d_in[1];
  const float* s_mu = (const float*)d_in[2];
  const float* s_sg = (const float*)d_in[3];
  const float* Wq = (const float*)d_in[4];
  const float* bq = (const float*)d_in[5];
  const float* Wk = (const float*)d_in[6];
  // d_in[7] = bk: unused (softmax-invariant)
  const float* Wv = (const float*)d_in[8];
  const float* bv = (const float*)d_in[9];
  const float* Wih = (const float*)d_in[10];
  const float* bih = (const float*)d_in[11];
  const float* Whh = (const float*)d_in[12];
  const float* bhh = (const float*)d_in[13];
  const float* W1 = (const float*)d_in[14];
  const float* b1 = (const float*)d_in[15];
  const float* W2 = (const float*)d_in[16];
  const float* b2 = (const float*)d_in[17];
  const float* gsl = (const float*)d_in[18];
  const float* bsl = (const float*)d_in[19];
  const float* gml = (const float*)d_in[20];
  const float* bml = (const float*)d_in[21];
  float* out = (float*)d_out;

  char* wsb = (char*)d_ws;
  unsigned* xbf = (unsigned*)wsb;  // bf16 copy of inputs: 128 MiB
  float* fp = (float*)(wsb + (size_t)Bn * Nn * Dd * 2);
  float* slots = fp; fp += Bn * Ss * Dd;
  float* qk = fp;    fp += Bn * Ss * Dd;
  float* bqk = fp;   fp += Dd;
  float* pl = fp;    fp += Bn * CH * Ss;
  float* pu = fp;    fp += Bn * CH * Ss * Dd;
  float* bzr = fp;   fp += 512;
  unsigned short* wb = (unsigned short*)fp;
  unsigned short* Wv_b = wb;  wb += 65536;
  unsigned short* Wzr_b = wb; wb += 262144;
  unsigned short* Win_b = wb; wb += 65536;
  unsigned short* Whn_b = wb; wb += 65536;
  unsigned short* W1_b = wb;  wb += 65536;
  unsigned short* W2_b = wb;  wb += 65536;
  unsigned short* Wqk_b = wb; wb += 65536;
  (void)in_sizes; (void)n_in; (void)out_size; (void)ws_size;

  k_wqk<<<dim3(257), dim3(256), 0, stream>>>(Wq, Wk, bq, Wqk_b, bqk);
  k_conv<<<dim3(1154), dim3(256), 0, stream>>>(
      Wv, Wih, Whh, W1, W2, bih, bhh, (unsigned*)Wv_b, (unsigned*)Wzr_b,
      (unsigned*)Win_b, (unsigned*)Whn_b, (unsigned*)W1_b, (unsigned*)W2_b, bzr);
  k_qk0<<<dim3(32), dim3(512), 0, stream>>>(noise, s_mu, s_sg, gsl, bsl, Wqk_b, bqk,
                                            slots, qk);
  for (int it = 0; it < 3; ++it) {
    if (it == 0)
      k_attn<true><<<dim3(CH, Bn), dim3(256), 0, stream>>>(inputs, xbf, qk, pl, pu);
    else
      k_attn<false><<<dim3(CH, Bn), dim3(256), 0, stream>>>(nullptr, xbf, qk, pl, pu);
    k_upd<<<dim3(32), dim3(512), 0, stream>>>(
        pl, pu, Wv_b, bv, Wzr_b, bzr, Win_b, bih + 512, Whn_b, bhh + 512, W1_b, b1,
        W2_b, b2, gml, bml, gsl, bsl, Wqk_b, bqk, slots, qk, (it == 2) ? out : nullptr);
  }
}